// Round 5
// baseline (222.880 us; speedup 1.0000x reference)
//
#include <hip/hip_runtime.h>

#define B 128
#define L 1024

#if __has_builtin(__builtin_amdgcn_exp2f)
#define EXP2(x) __builtin_amdgcn_exp2f(x)
#else
#define EXP2(x) __expf((x) * 0.6931471805599453f)
#endif

// ws layout (floats):
//   [0 .. 524288)    E partials: idx = jseg*(B*L) + b*L + i   (2 MB)
//   [524288..524416) per-row arrival counters (int)
//   [524416]         ndcg accumulator
//   [524417]         global row-completion counter (int)
#define WS_E    0
#define WS_CTR  524288
#define WS_ACC  524416
#define WS_GCTR 524417

__global__ __launch_bounds__(256) void init_ws(float* ws) {
    int t = threadIdx.x;
    if (t < 130) ws[WS_CTR + t] = 0.0f;   // zeroes counters + acc + gctr
}

// Phi(diff/sqrt2) via erf(y), y = diff/2 prescaled:
//   erfc(|y|) ~= exp(-(1.12838 y + 0.6446 y^2 + 0.0745 y^3)), |dPhi| <= ~2.5e-4
// Constants pre-multiplied by -log2(e) for v_exp_f32.
// Per pair: sub, fma, fma, mul, exp2, sub, bfi, add = 7 full-rate + 1 trans.
#define K1 -1.6279072f
#define K2 -0.9299637f
#define K3 -0.1074808f

__device__ __forceinline__ float erf_term(float pi, float pj) {
    float d = pi - pj;
    float a = __builtin_fabsf(d);
    float t = __builtin_fmaf(K3, a, K2);
    float u = __builtin_fmaf(t, a, K1);
    float e = EXP2(a * u);                   // ~= erfc(|y|)
    return __builtin_copysignf(1.0f - e, d); // = erf(y)
}

// grid = B*16 blocks, 256 threads. blk -> (b, iseg, jseg): partial E sums for
// i in iseg over j in jseg. Last-arriving block of the 16 per row runs the
// row epilogue; last row overall writes the final scalar.
__global__ __launch_bounds__(256, 8) void pair_kernel(const float* __restrict__ preds,
                                                      const float* __restrict__ target,
                                                      float* __restrict__ ws,
                                                      float* __restrict__ out) {
    __shared__ float sj[256];
    __shared__ float wdummy; (void)wdummy;
    __shared__ unsigned long long cred[256];
    __shared__ float2 fred[256];
    __shared__ int lastflag;

    const int blk  = blockIdx.x;
    const int b    = blk >> 4;
    const int iseg = (blk >> 2) & 3;
    const int jseg = blk & 3;
    const int tid  = threadIdx.x;

    const float* prow = preds + b * L;

    // stage j-segment prescaled by 0.5 (erf argument is diff/2)
    if (tid < 64) {
        float4 v = reinterpret_cast<const float4*>(prow + jseg * 256)[tid];
        v.x *= 0.5f; v.y *= 0.5f; v.z *= 0.5f; v.w *= 0.5f;
        reinterpret_cast<float4*>(sj)[tid] = v;
    }
    const int i  = iseg * 256 + tid;
    const float pi = 0.5f * prow[i];
    __syncthreads();

    float a0 = 0.f, a1 = 0.f, a2 = 0.f, a3 = 0.f,
          a4 = 0.f, a5 = 0.f, a6 = 0.f, a7 = 0.f;
    for (int j = 0; j < 256; j += 8) {
        float4 va = *reinterpret_cast<const float4*>(&sj[j]);
        float4 vb = *reinterpret_cast<const float4*>(&sj[j + 4]);
        a0 += erf_term(pi, va.x);
        a1 += erf_term(pi, va.y);
        a2 += erf_term(pi, va.z);
        a3 += erf_term(pi, va.w);
        a4 += erf_term(pi, vb.x);
        a5 += erf_term(pi, vb.y);
        a6 += erf_term(pi, vb.z);
        a7 += erf_term(pi, vb.w);
    }
    float E = ((a0 + a1) + (a2 + a3)) + ((a4 + a5) + (a6 + a7));

    // publish partial (device-scope, coalesced layout), then arrive
    __hip_atomic_store(&ws[WS_E + jseg * (B * L) + b * L + i], E,
                       __ATOMIC_RELAXED, __HIP_MEMORY_SCOPE_AGENT);
    __threadfence();
    __syncthreads();
    if (tid == 0) {
        int old = atomicAdd((int*)ws + WS_CTR + b, 1);
        lastflag = (old == 15);
    }
    __syncthreads();
    if (!lastflag) return;

    // ---- row epilogue (one block per row) ----
    __threadfence();  // acquire
    const float* trow = target + b * L;

    float dcg_p = 0.0f;
    unsigned long long cnt = 0ull;
    #pragma unroll
    for (int k = 0; k < 4; ++k) {
        int ii = tid + k * 256;
        float Es = 0.0f;
        #pragma unroll
        for (int js = 0; js < 4; ++js)
            Es += __hip_atomic_load(&ws[WS_E + js * (B * L) + b * L + ii],
                                    __ATOMIC_RELAXED, __HIP_MEMORY_SCOPE_AGENT);
        // sum_j Phi = L/2 + Es/2 (diag = 0.5 exactly); er+1 = 513.5 + Es/2
        float er1 = 513.5f + 0.5f * Es;
        float t = trow[ii];
        float g = EXP2(t) - 1.0f;            // 2^t - 1, exact for integer grades
        dcg_p += g * __builtin_amdgcn_rcpf(__log2f(er1));
        cnt += ((unsigned long long)(t > 3.5f) << 48)
             + ((unsigned long long)(t > 2.5f) << 32)
             + ((unsigned long long)(t > 1.5f) << 16)
             + ((unsigned long long)(t > 0.5f));
    }
    cred[tid] = cnt;
    __syncthreads();
    #pragma unroll
    for (int s = 128; s > 0; s >>= 1) {
        if (tid < (unsigned)s) cred[tid] += cred[tid + s];
        __syncthreads();
    }
    unsigned long long tot = cred[0];
    const int n4 = (int)(tot >> 48) & 0xFFFF;
    const int n3 = (int)(tot >> 32) & 0xFFFF;
    const int n2 = (int)(tot >> 16) & 0xFFFF;
    const int n1 = (int)(tot)       & 0xFFFF;

    float idcg_p = 0.0f;
    #pragma unroll
    for (int k = 0; k < 4; ++k) {
        int pos = tid + 1 + k * 256;
        float gain = (pos <= n4) ? 15.0f : (pos <= n3) ? 7.0f :
                     (pos <= n2) ? 3.0f  : (pos <= n1) ? 1.0f : 0.0f;
        idcg_p += gain * __builtin_amdgcn_rcpf(__log2f((float)pos + 1.0f));
    }
    fred[tid] = make_float2(dcg_p, idcg_p);
    __syncthreads();
    #pragma unroll
    for (int s = 128; s > 0; s >>= 1) {
        if (tid < (unsigned)s) {
            float2 x = fred[tid], y = fred[tid + s];
            fred[tid] = make_float2(x.x + y.x, x.y + y.y);
        }
        __syncthreads();
    }

    if (tid == 0) {
        float ndcg = fred[0].x / (fred[0].y + 1e-10f);
        atomicAdd(&ws[WS_ACC], ndcg);
        __threadfence();
        int old2 = atomicAdd((int*)ws + WS_GCTR, 1);
        if (old2 == B - 1) {
            __threadfence();
            float acc = __hip_atomic_load(&ws[WS_ACC], __ATOMIC_RELAXED,
                                          __HIP_MEMORY_SCOPE_AGENT);
            out[0] = -acc * (1.0f / (float)B);
        }
    }
}

extern "C" void kernel_launch(void* const* d_in, const int* in_sizes, int n_in,
                              void* d_out, int out_size, void* d_ws, size_t ws_size,
                              hipStream_t stream) {
    const float* preds  = (const float*)d_in[0];
    const float* target = (const float*)d_in[1];
    float* out = (float*)d_out;
    float* ws  = (float*)d_ws;

    init_ws<<<1, 256, 0, stream>>>(ws);
    pair_kernel<<<B * 16, 256, 0, stream>>>(preds, target, ws, out);
}

// Round 6
// 124.282 us; speedup vs baseline: 1.7933x; 1.7933x over previous
//
#include <hip/hip_runtime.h>

#define B 128
#define L 1024

#if __has_builtin(__builtin_amdgcn_exp2f)
#define EXP2(x) __builtin_amdgcn_exp2f(x)
#else
#define EXP2(x) __expf((x) * 0.6931471805599453f)
#endif

// ws layout (floats):
//   [0..128)    dcg[b] accumulators
//   [128..256)  per-row arrival counters (int)
//   [256]       ndcg accumulator
//   [257]       global row-completion counter (int)
#define WS_DCG  0
#define WS_CTR  128
#define WS_ACC  256
#define WS_GCTR 257

__global__ __launch_bounds__(256) void init_ws(float* ws) {
    int t = threadIdx.x;
    if (t < 130) ws[WS_DCG + ((t < 128) ? t : (128 + t))] = 0.0f; // [0..128) and [256],[257]
    if (t >= 128 && t < 256) ws[t] = 0.0f;                        // counters
}

// Phi(diff/sqrt2) via erf(y), y = diff/2 prescaled into LDS:
//   erfc(|y|) ~= exp(-(1.12838 y + 0.6446 y^2 + 0.0745 y^3)), |dPhi| <= ~2.5e-4
// Constants pre-multiplied by -log2(e) for v_exp_f32.
// Per pair: sub, fma, fma, mul, exp2, sub, bfi, add = 7 full-rate + 1 trans.
#define K1 -1.6279072f
#define K2 -0.9299637f
#define K3 -0.1074808f

__device__ __forceinline__ float erf_term(float pi, float pj) {
    float d = pi - pj;
    float a = __builtin_fabsf(d);
    float t = __builtin_fmaf(K3, a, K2);
    float u = __builtin_fmaf(t, a, K1);
    float e = EXP2(a * u);                   // ~= erfc(|y|)
    return __builtin_copysignf(1.0f - e, d); // = erf(y)
}

// grid = B*16 blocks, 256 threads. Block (b, iseg) owns 64 i's; thread
// (i_local = tid&63, jseg = tid>>6) sums its 256-j segment from LDS.
// Cross-jseg reduction in LDS (no global partials, no device fences in the
// hot path — R5's cross-XCD partial traffic was a 2.3x regression).
// Last-arriving block of the 16 per row runs the fused row epilogue.
__global__ __launch_bounds__(256, 8) void pair_kernel(const float* __restrict__ preds,
                                                      const float* __restrict__ target,
                                                      float* __restrict__ ws,
                                                      float* __restrict__ out) {
    __shared__ float sp[L];                 // prescaled row
    __shared__ float red[256];              // cross-wave E reduction
    __shared__ unsigned long long cred[256];
    __shared__ float2 fred[256];
    __shared__ int lastflag;

    const int blk  = blockIdx.x;
    const int b    = blk >> 4;
    const int iseg = blk & 15;
    const int tid  = threadIdx.x;
    const int il   = tid & 63;              // i_local
    const int jseg = tid >> 6;              // 0..3 (wave id)

    const float* prow = preds + b * L;
    const float* trow = target + b * L;

    // stage full row prescaled by 0.5 (erf argument is diff/2)
    float4 v4 = reinterpret_cast<const float4*>(prow)[tid];
    v4.x *= 0.5f; v4.y *= 0.5f; v4.z *= 0.5f; v4.w *= 0.5f;
    reinterpret_cast<float4*>(sp)[tid] = v4;
    __syncthreads();

    const int i = iseg * 64 + il;
    const float pi = sp[i];
    const float* sj = &sp[jseg * 256];

    float a0 = 0.f, a1 = 0.f, a2 = 0.f, a3 = 0.f,
          a4 = 0.f, a5 = 0.f, a6 = 0.f, a7 = 0.f;
    for (int j = 0; j < 256; j += 8) {
        float4 va = *reinterpret_cast<const float4*>(&sj[j]);
        float4 vb = *reinterpret_cast<const float4*>(&sj[j + 4]);
        a0 += erf_term(pi, va.x);
        a1 += erf_term(pi, va.y);
        a2 += erf_term(pi, va.z);
        a3 += erf_term(pi, va.w);
        a4 += erf_term(pi, vb.x);
        a5 += erf_term(pi, vb.y);
        a6 += erf_term(pi, vb.z);
        a7 += erf_term(pi, vb.w);
    }
    float E = ((a0 + a1) + (a2 + a3)) + ((a4 + a5) + (a6 + a7));

    // cross-jseg combine in LDS
    red[tid] = E;
    __syncthreads();

    float contrib = 0.0f;
    if (tid < 64) {
        float Es = ((red[tid] + red[tid + 64]) + (red[tid + 128] + red[tid + 192]));
        // sum_j Phi = L/2 + Es/2 (diag contributes exactly 0.5); er+1 = 513.5 + Es/2
        float er1 = 513.5f + 0.5f * Es;
        float g = EXP2(trow[i]) - 1.0f;     // 2^t - 1, exact for integer grades
        contrib = g * __builtin_amdgcn_rcpf(__log2f(er1));
        #pragma unroll
        for (int off = 32; off > 0; off >>= 1)
            contrib += __shfl_down(contrib, off);
    }
    if (tid == 0) {
        atomicAdd(&ws[WS_DCG + b], contrib);
        __threadfence();
        int old = atomicAdd((int*)ws + WS_CTR + b, 1);
        lastflag = (old == 15);
    }
    __syncthreads();
    if (!lastflag) return;

    // ---- row epilogue (one block per row): counting-sort IDCG + ndcg ----
    __threadfence();  // acquire: order dcg read after counter
    unsigned long long cnt = 0ull;
    #pragma unroll
    for (int k = 0; k < 4; ++k) {
        float t = trow[tid + k * 256];
        cnt += ((unsigned long long)(t > 3.5f) << 48)
             + ((unsigned long long)(t > 2.5f) << 32)
             + ((unsigned long long)(t > 1.5f) << 16)
             + ((unsigned long long)(t > 0.5f));
    }
    cred[tid] = cnt;
    __syncthreads();
    #pragma unroll
    for (int s = 128; s > 0; s >>= 1) {
        if (tid < (unsigned)s) cred[tid] += cred[tid + s];
        __syncthreads();
    }
    unsigned long long tot = cred[0];
    const int n4 = (int)(tot >> 48) & 0xFFFF;
    const int n3 = (int)(tot >> 32) & 0xFFFF;
    const int n2 = (int)(tot >> 16) & 0xFFFF;
    const int n1 = (int)(tot)       & 0xFFFF;

    float idcg_p = 0.0f;
    #pragma unroll
    for (int k = 0; k < 4; ++k) {
        int pos = tid + 1 + k * 256;
        float gain = (pos <= n4) ? 15.0f : (pos <= n3) ? 7.0f :
                     (pos <= n2) ? 3.0f  : (pos <= n1) ? 1.0f : 0.0f;
        idcg_p += gain * __builtin_amdgcn_rcpf(__log2f((float)pos + 1.0f));
    }
    fred[tid] = make_float2(idcg_p, 0.0f);
    __syncthreads();
    #pragma unroll
    for (int s = 128; s > 0; s >>= 1) {
        if (tid < (unsigned)s) {
            fred[tid].x += fred[tid + s].x;
        }
        __syncthreads();
    }

    if (tid == 0) {
        float dcgv = atomicAdd(&ws[WS_DCG + b], 0.0f);  // coherent read of full dcg[b]
        float ndcg = dcgv / (fred[0].x + 1e-10f);
        atomicAdd(&ws[WS_ACC], ndcg);
        __threadfence();
        int old2 = atomicAdd((int*)ws + WS_GCTR, 1);
        if (old2 == B - 1) {
            float acc = atomicAdd(&ws[WS_ACC], 0.0f);   // coherent read of final sum
            out[0] = -acc * (1.0f / (float)B);
        }
    }
}

extern "C" void kernel_launch(void* const* d_in, const int* in_sizes, int n_in,
                              void* d_out, int out_size, void* d_ws, size_t ws_size,
                              hipStream_t stream) {
    const float* preds  = (const float*)d_in[0];
    const float* target = (const float*)d_in[1];
    float* out = (float*)d_out;
    float* ws  = (float*)d_ws;

    init_ws<<<1, 256, 0, stream>>>(ws);
    pair_kernel<<<B * 16, 256, 0, stream>>>(preds, target, ws, out);
}

// Round 7
// 90.341 us; speedup vs baseline: 2.4671x; 1.3757x over previous
//
#include <hip/hip_runtime.h>

#define B 128
#define L 1024

#if __has_builtin(__builtin_amdgcn_exp2f)
#define EXP2(x) __builtin_amdgcn_exp2f(x)
#else
#define EXP2(x) __expf((x) * 0.6931471805599453f)
#endif

// ws layout (floats):
//   [0..2048)  per-wave dcg partials: idx = blk*2 + wave  (blk = b*8+iseg)
//   [2048]     ndcg accumulator      (zeroed by pair_kernel block 0)
//   [2049]     completion counter    (zeroed by pair_kernel block 0)
#define WS_ACC  2048
#define WS_GCTR 2049

// Phi(diff/sqrt2) via erf(y), y = diff/2 prescaled into LDS:
//   erfc(|y|) ~= exp(-(1.12838 y + 0.6446 y^2 + 0.0745 y^3)), |dPhi| <= ~2.5e-4
// Constants pre-multiplied by -log2(e) for v_exp_f32.
// Per pair: sub, fma(abs-mod), fma, mul, exp2(4 slots), sub, bfi, add = 11 lane-slots.
#define K1 -1.6279072f
#define K2 -0.9299637f
#define K3 -0.1074808f

__device__ __forceinline__ float erf_term(float pi, float pj) {
    float d = pi - pj;
    float a = __builtin_fabsf(d);
    float t = __builtin_fmaf(K3, a, K2);
    float u = __builtin_fmaf(t, a, K1);
    float e = EXP2(a * u);                   // ~= erfc(|y|)
    return __builtin_copysignf(1.0f - e, d); // = erf(y)
}

// grid = B*8 blocks, 256 threads, 4 blocks/CU -> 4 waves/SIMD (vs R4's 2).
// Block (b, iseg) owns 128 i's; thread (il = tid&127, jh = tid>>7) sums its
// 512-j half from LDS. NO atomics/fences in this kernel (R6 lesson: device
// fences in the hot path dominate); per-wave dcg partials plain-stored to
// disjoint ws slots. Epilogue lives in the separate finish_kernel.
__global__ __launch_bounds__(256, 8) void pair_kernel(const float* __restrict__ preds,
                                                      const float* __restrict__ target,
                                                      float* __restrict__ ws) {
    __shared__ float sp[L];                 // prescaled row
    __shared__ float red[256];              // cross-half E reduction

    const int blk  = blockIdx.x;
    const int b    = blk >> 3;
    const int iseg = blk & 7;
    const int tid  = threadIdx.x;
    const int il   = tid & 127;             // i_local
    const int jh   = tid >> 7;              // j half (0/1)

    if (blk == 0 && tid == 0) {
        ws[WS_ACC] = 0.0f;                  // visible to finish_kernel at
        ((int*)ws)[WS_GCTR] = 0;            // dispatch boundary
    }

    const float* prow = preds + b * L;

    // stage full row prescaled by 0.5 (erf argument is diff/2)
    float4 v4 = reinterpret_cast<const float4*>(prow)[tid];
    v4.x *= 0.5f; v4.y *= 0.5f; v4.z *= 0.5f; v4.w *= 0.5f;
    reinterpret_cast<float4*>(sp)[tid] = v4;

    const int i = iseg * 128 + il;
    const float tgt = (tid < 128) ? target[b * L + i] : 0.0f;  // hoisted

    __syncthreads();

    const float pi = sp[i];
    const float* sj = &sp[jh * 512];

    float a0 = 0.f, a1 = 0.f, a2 = 0.f, a3 = 0.f,
          a4 = 0.f, a5 = 0.f, a6 = 0.f, a7 = 0.f;
    for (int j = 0; j < 512; j += 8) {
        float4 va = *reinterpret_cast<const float4*>(&sj[j]);
        float4 vb = *reinterpret_cast<const float4*>(&sj[j + 4]);
        a0 += erf_term(pi, va.x);
        a1 += erf_term(pi, va.y);
        a2 += erf_term(pi, va.z);
        a3 += erf_term(pi, va.w);
        a4 += erf_term(pi, vb.x);
        a5 += erf_term(pi, vb.y);
        a6 += erf_term(pi, vb.z);
        a7 += erf_term(pi, vb.w);
    }
    float E = ((a0 + a1) + (a2 + a3)) + ((a4 + a5) + (a6 + a7));

    // cross-half combine in LDS; lower 128 threads (2 waves) finish the i's
    red[tid] = E;
    __syncthreads();

    if (tid < 128) {
        float Es = red[tid] + red[tid + 128];
        // sum_j Phi = L/2 + Es/2 (diag contributes exactly 0.5); er+1 = 513.5 + Es/2
        float er1 = 513.5f + 0.5f * Es;
        float g = EXP2(tgt) - 1.0f;          // 2^t - 1, exact for integer grades
        float contrib = g * __builtin_amdgcn_rcpf(__log2f(er1));
        #pragma unroll
        for (int off = 32; off > 0; off >>= 1)
            contrib += __shfl_down(contrib, off);
        if ((tid & 63) == 0)
            ws[blk * 2 + (tid >> 6)] = contrib;   // plain store, disjoint slot
    }
}

// grid = B blocks, 256 threads. Block b: combine 16 dcg partials, counting-sort
// IDCG (grades are ints 0..4), ndcg; last block writes the final scalar.
__global__ __launch_bounds__(256) void finish_kernel(const float* __restrict__ target,
                                                     float* __restrict__ ws,
                                                     float* __restrict__ out) {
    __shared__ unsigned long long cred[256];
    __shared__ float2 fred[256];

    const int b   = blockIdx.x;
    const int tid = threadIdx.x;
    const float* trow = target + b * L;

    // packed 16-bit counts of grades >=4,>=3,>=2,>=1 (max 1024 fits)
    unsigned long long cnt = 0ull;
    #pragma unroll
    for (int k = 0; k < 4; ++k) {
        float t = trow[tid + k * 256];
        cnt += ((unsigned long long)(t > 3.5f) << 48)
             + ((unsigned long long)(t > 2.5f) << 32)
             + ((unsigned long long)(t > 1.5f) << 16)
             + ((unsigned long long)(t > 0.5f));
    }
    cred[tid] = cnt;
    __syncthreads();
    #pragma unroll
    for (int s = 128; s > 0; s >>= 1) {
        if (tid < (unsigned)s) cred[tid] += cred[tid + s];
        __syncthreads();
    }
    unsigned long long tot = cred[0];
    const int n4 = (int)(tot >> 48) & 0xFFFF;
    const int n3 = (int)(tot >> 32) & 0xFFFF;
    const int n2 = (int)(tot >> 16) & 0xFFFF;
    const int n1 = (int)(tot)       & 0xFFFF;

    // parallel IDCG; joint reduction with the 16 dcg partials of this row
    float idcg_p = 0.0f;
    #pragma unroll
    for (int k = 0; k < 4; ++k) {
        int pos = tid + 1 + k * 256;
        float gain = (pos <= n4) ? 15.0f : (pos <= n3) ? 7.0f :
                     (pos <= n2) ? 3.0f  : (pos <= n1) ? 1.0f : 0.0f;
        idcg_p += gain * __builtin_amdgcn_rcpf(__log2f((float)pos + 1.0f));
    }
    float dcg_p = (tid < 16) ? ws[b * 16 + tid] : 0.0f;
    fred[tid] = make_float2(idcg_p, dcg_p);
    __syncthreads();
    #pragma unroll
    for (int s = 128; s > 0; s >>= 1) {
        if (tid < (unsigned)s) {
            float2 x = fred[tid], y = fred[tid + s];
            fred[tid] = make_float2(x.x + y.x, x.y + y.y);
        }
        __syncthreads();
    }

    if (tid == 0) {
        float ndcg = fred[0].y / (fred[0].x + 1e-10f);
        atomicAdd(&ws[WS_ACC], ndcg);
        __threadfence();
        int old = atomicAdd((int*)ws + WS_GCTR, 1);
        if (old == B - 1) {
            float acc = atomicAdd(&ws[WS_ACC], 0.0f);  // coherent read
            out[0] = -acc * (1.0f / (float)B);
        }
    }
}

extern "C" void kernel_launch(void* const* d_in, const int* in_sizes, int n_in,
                              void* d_out, int out_size, void* d_ws, size_t ws_size,
                              hipStream_t stream) {
    const float* preds  = (const float*)d_in[0];
    const float* target = (const float*)d_in[1];
    float* out = (float*)d_out;
    float* ws  = (float*)d_ws;

    pair_kernel<<<B * 8, 256, 0, stream>>>(preds, target, ws);
    finish_kernel<<<B, 256, 0, stream>>>(target, ws, out);
}

// Round 8
// 89.027 us; speedup vs baseline: 2.5035x; 1.0148x over previous
//
#include <hip/hip_runtime.h>

#define B 128
#define L 1024

#if __has_builtin(__builtin_amdgcn_exp2f)
#define EXP2(x) __builtin_amdgcn_exp2f(x)
#else
#define EXP2(x) __expf((x) * 0.6931471805599453f)
#endif

typedef float v2f __attribute__((ext_vector_type(2)));

// ws layout (floats):
//   [0..2048)  per-wave dcg partials: idx = blk*2 + wave  (blk = b*8+iseg)
//   [2048]     ndcg accumulator      (zeroed by pair_kernel block 0)
//   [2049]     completion counter    (zeroed by pair_kernel block 0)
#define WS_ACC  2048
#define WS_GCTR 2049

// Phi(diff/sqrt2) via erf(y), y = diff/2 prescaled into LDS:
//   erfc(|y|) ~= exp(-(1.12838 y + 0.6446 y^2 + 0.0745 y^3)), |dPhi| <= ~2.5e-4
// Constants pre-multiplied by -log2(e) for v_exp_f32.
// Packed fp32 (v_pk_*) processes 2 pairs per slot for everything but the exp:
// per 2 pairs: pk_sub, pk_abs, 2x pk_fma(->mul), 2x v_exp, pk_sub, 2x bfi,
// pk_add = ~17 lane-slots -> 8.5/pair (vs 11 scalar).
#define K1 -1.6279072f
#define K2 -0.9299637f
#define K3 -0.1074808f

__device__ __forceinline__ v2f erf_term2(v2f pi2, v2f pj) {
    v2f d = pi2 - pj;
    v2f a = __builtin_elementwise_abs(d);
    v2f t = __builtin_elementwise_fma(a, (v2f){K3, K3}, (v2f){K2, K2});
    v2f u = __builtin_elementwise_fma(t, a, (v2f){K1, K1});
    v2f w = a * u;
    v2f e;
    e.x = EXP2(w.x);                         // ~= erfc(|y|), trans pipe (scalar)
    e.y = EXP2(w.y);
    v2f r = (v2f){1.0f, 1.0f} - e;
    return __builtin_elementwise_copysign(r, d);  // = erf(y), 2 lanes
}

// grid = B*8 blocks, 256 threads, 4 blocks/CU -> 4 waves/SIMD.
// Block (b, iseg) owns 128 i's; thread (il = tid&127, jh = tid>>7) sums its
// 512-j half from LDS via packed-fp32 math. NO atomics/fences here (R6
// lesson); per-wave dcg partials plain-stored to disjoint ws slots.
__global__ __launch_bounds__(256, 8) void pair_kernel(const float* __restrict__ preds,
                                                      const float* __restrict__ target,
                                                      float* __restrict__ ws) {
    __shared__ float sp[L];                 // prescaled row
    __shared__ float red[256];              // cross-half E reduction

    const int blk  = blockIdx.x;
    const int b    = blk >> 3;
    const int iseg = blk & 7;
    const int tid  = threadIdx.x;
    const int il   = tid & 127;             // i_local
    const int jh   = tid >> 7;              // j half (0/1)

    if (blk == 0 && tid == 0) {
        ws[WS_ACC] = 0.0f;                  // visible to finish_kernel at
        ((int*)ws)[WS_GCTR] = 0;            // dispatch boundary
    }

    const float* prow = preds + b * L;

    // stage full row prescaled by 0.5 (erf argument is diff/2)
    float4 v4 = reinterpret_cast<const float4*>(prow)[tid];
    v4.x *= 0.5f; v4.y *= 0.5f; v4.z *= 0.5f; v4.w *= 0.5f;
    reinterpret_cast<float4*>(sp)[tid] = v4;

    const int i = iseg * 128 + il;
    const float tgt = (tid < 128) ? target[b * L + i] : 0.0f;  // hoisted

    __syncthreads();

    const float pif = sp[i];
    const v2f pi2 = {pif, pif};
    const float* sj = &sp[jh * 512];

    v2f a0 = {0.f, 0.f}, a1 = {0.f, 0.f}, a2 = {0.f, 0.f}, a3 = {0.f, 0.f},
        a4 = {0.f, 0.f}, a5 = {0.f, 0.f}, a6 = {0.f, 0.f}, a7 = {0.f, 0.f};
    for (int j = 0; j < 512; j += 16) {
        float4 q0 = *reinterpret_cast<const float4*>(&sj[j]);
        float4 q1 = *reinterpret_cast<const float4*>(&sj[j + 4]);
        float4 q2 = *reinterpret_cast<const float4*>(&sj[j + 8]);
        float4 q3 = *reinterpret_cast<const float4*>(&sj[j + 12]);
        a0 += erf_term2(pi2, (v2f){q0.x, q0.y});
        a1 += erf_term2(pi2, (v2f){q0.z, q0.w});
        a2 += erf_term2(pi2, (v2f){q1.x, q1.y});
        a3 += erf_term2(pi2, (v2f){q1.z, q1.w});
        a4 += erf_term2(pi2, (v2f){q2.x, q2.y});
        a5 += erf_term2(pi2, (v2f){q2.z, q2.w});
        a6 += erf_term2(pi2, (v2f){q3.x, q3.y});
        a7 += erf_term2(pi2, (v2f){q3.z, q3.w});
    }
    v2f Ev = ((a0 + a1) + (a2 + a3)) + ((a4 + a5) + (a6 + a7));
    float E = Ev.x + Ev.y;

    // cross-half combine in LDS; lower 128 threads (2 waves) finish the i's
    red[tid] = E;
    __syncthreads();

    if (tid < 128) {
        float Es = red[tid] + red[tid + 128];
        // sum_j Phi = L/2 + Es/2 (diag contributes exactly 0.5); er+1 = 513.5 + Es/2
        float er1 = 513.5f + 0.5f * Es;
        float g = EXP2(tgt) - 1.0f;          // 2^t - 1, exact for integer grades
        float contrib = g * __builtin_amdgcn_rcpf(__log2f(er1));
        #pragma unroll
        for (int off = 32; off > 0; off >>= 1)
            contrib += __shfl_down(contrib, off);
        if ((tid & 63) == 0)
            ws[blk * 2 + (tid >> 6)] = contrib;   // plain store, disjoint slot
    }
}

// grid = B blocks, 256 threads. Block b: combine 16 dcg partials, counting-sort
// IDCG (grades are ints 0..4), ndcg; last block writes the final scalar.
__global__ __launch_bounds__(256) void finish_kernel(const float* __restrict__ target,
                                                     float* __restrict__ ws,
                                                     float* __restrict__ out) {
    __shared__ unsigned long long cred[256];
    __shared__ float2 fred[256];

    const int b   = blockIdx.x;
    const int tid = threadIdx.x;
    const float* trow = target + b * L;

    // packed 16-bit counts of grades >=4,>=3,>=2,>=1 (max 1024 fits)
    unsigned long long cnt = 0ull;
    #pragma unroll
    for (int k = 0; k < 4; ++k) {
        float t = trow[tid + k * 256];
        cnt += ((unsigned long long)(t > 3.5f) << 48)
             + ((unsigned long long)(t > 2.5f) << 32)
             + ((unsigned long long)(t > 1.5f) << 16)
             + ((unsigned long long)(t > 0.5f));
    }
    cred[tid] = cnt;
    __syncthreads();
    #pragma unroll
    for (int s = 128; s > 0; s >>= 1) {
        if (tid < (unsigned)s) cred[tid] += cred[tid + s];
        __syncthreads();
    }
    unsigned long long tot = cred[0];
    const int n4 = (int)(tot >> 48) & 0xFFFF;
    const int n3 = (int)(tot >> 32) & 0xFFFF;
    const int n2 = (int)(tot >> 16) & 0xFFFF;
    const int n1 = (int)(tot)       & 0xFFFF;

    // parallel IDCG; joint reduction with the 16 dcg partials of this row
    float idcg_p = 0.0f;
    #pragma unroll
    for (int k = 0; k < 4; ++k) {
        int pos = tid + 1 + k * 256;
        float gain = (pos <= n4) ? 15.0f : (pos <= n3) ? 7.0f :
                     (pos <= n2) ? 3.0f  : (pos <= n1) ? 1.0f : 0.0f;
        idcg_p += gain * __builtin_amdgcn_rcpf(__log2f((float)pos + 1.0f));
    }
    float dcg_p = (tid < 16) ? ws[b * 16 + tid] : 0.0f;
    fred[tid] = make_float2(idcg_p, dcg_p);
    __syncthreads();
    #pragma unroll
    for (int s = 128; s > 0; s >>= 1) {
        if (tid < (unsigned)s) {
            float2 x = fred[tid], y = fred[tid + s];
            fred[tid] = make_float2(x.x + y.x, x.y + y.y);
        }
        __syncthreads();
    }

    if (tid == 0) {
        float ndcg = fred[0].y / (fred[0].x + 1e-10f);
        atomicAdd(&ws[WS_ACC], ndcg);
        __threadfence();
        int old = atomicAdd((int*)ws + WS_GCTR, 1);
        if (old == B - 1) {
            float acc = atomicAdd(&ws[WS_ACC], 0.0f);  // coherent read
            out[0] = -acc * (1.0f / (float)B);
        }
    }
}

extern "C" void kernel_launch(void* const* d_in, const int* in_sizes, int n_in,
                              void* d_out, int out_size, void* d_ws, size_t ws_size,
                              hipStream_t stream) {
    const float* preds  = (const float*)d_in[0];
    const float* target = (const float*)d_in[1];
    float* out = (float*)d_out;
    float* ws  = (float*)d_ws;

    pair_kernel<<<B * 8, 256, 0, stream>>>(preds, target, ws);
    finish_kernel<<<B, 256, 0, stream>>>(target, ws, out);
}